// Round 11
// baseline (1854.122 us; speedup 1.0000x reference)
//
#include <hip/hip_runtime.h>
#include <math.h>

// Problem constants
#define NN 400
#define TPB 512          // 8 waves, 2 waves/SIMD; 3 register A-tiles/wave (156 regs, fits),
                         // 2 static tiles streamed from LDS; ca*et bias fused into K-rows 401-403
#define KP 424           // padded K stride in fp16 elems

// workspace layout (32-bit indices)
#define XRAW_OFF 1024    // 3200 floats
#define HINP_OFF 4224    // 400 floats
#define CL_OFF   4624    // 2400 floats (projected readout c from k_pre2)

#define TAU_X 0.05f
#define TAU_M 0.2f
#define A1C 0.16f
#define A2C 0.048f
#define A3C 0.045f
#define DHC 0.001f
#define L1C 0.3f
#define L2C 0.33f

typedef unsigned long long ull;
typedef _Float16 f16;
typedef _Float16 __attribute__((ext_vector_type(8))) half8;
typedef float __attribute__((ext_vector_type(4))) f32x4;

// K1: xraw[n][b] = (top_obs @ xstars_prms)[n,b] + xstars_tar[b][n]; hinp[n] = spont[n]-(W@spont)[n]
__global__ __launch_bounds__(64) void k_pre1(const float* __restrict__ topo,
        const float* __restrict__ xp, const float* __restrict__ W,
        const float* __restrict__ sp, const float* __restrict__ iw,
        const float* __restrict__ des, float* __restrict__ ws)
{
    const int n = blockIdx.x, lane = threadIdx.x;
    float a0=0,a1=0,a2=0,a3=0,a4=0,a5=0,a6=0,a7=0, ah=0;
    for (int k = lane; k < NN; k += 64) {
        float to = topo[n*NN + k];
        float wv = W[n*NN + k];
        float s  = sp[k];
        const float* xr = xp + k*8;
        a0 = fmaf(to, xr[0], a0); a1 = fmaf(to, xr[1], a1);
        a2 = fmaf(to, xr[2], a2); a3 = fmaf(to, xr[3], a3);
        a4 = fmaf(to, xr[4], a4); a5 = fmaf(to, xr[5], a5);
        a6 = fmaf(to, xr[6], a6); a7 = fmaf(to, xr[7], a7);
        ah = fmaf(wv, s, ah);
    }
    #pragma unroll
    for (int m = 1; m < 64; m <<= 1) {
        a0 += __shfl_xor(a0, m, 64); a1 += __shfl_xor(a1, m, 64);
        a2 += __shfl_xor(a2, m, 64); a3 += __shfl_xor(a3, m, 64);
        a4 += __shfl_xor(a4, m, 64); a5 += __shfl_xor(a5, m, 64);
        a6 += __shfl_xor(a6, m, 64); a7 += __shfl_xor(a7, m, 64);
        ah += __shfl_xor(ah, m, 64);
    }
    if (lane == 0) {
        float av[8] = {a0,a1,a2,a3,a4,a5,a6,a7};
        float w0 = iw[n*10 + 0], w1 = iw[n*10 + 1];
        #pragma unroll
        for (int b = 0; b < 8; ++b) {
            float j0 = des[2*b]   - 0.25f;
            float j1 = des[2*b+1] - 0.25f;
            ws[XRAW_OFF + n*8 + b] = av[b] + j0*w0 + j1*w1;
        }
        ws[HINP_OFF + n] = sp[n] - ah;
    }
}

// K2: scale s, Gram solve (fp64), Q, Cl precompute
__global__ __launch_bounds__(64) void k_pre2(const float* __restrict__ cp,
        const float* __restrict__ sp, float* __restrict__ ws)
{
    __shared__ float part[99][65];
    __shared__ float red[99];
    const int lane = threadIdx.x;
    float Sxx[36], Sxs[8], Praw[48], Ps[6];
    float Sss = 0.f;
    #pragma unroll
    for (int q = 0; q < 36; ++q) Sxx[q] = 0.f;
    #pragma unroll
    for (int q = 0; q < 8; ++q) Sxs[q] = 0.f;
    #pragma unroll
    for (int q = 0; q < 48; ++q) Praw[q] = 0.f;
    #pragma unroll
    for (int q = 0; q < 6; ++q) Ps[q] = 0.f;

    for (int n = lane; n < NN; n += 64) {
        float xr[8];
        #pragma unroll
        for (int j = 0; j < 8; ++j) xr[j] = ws[XRAW_OFF + n*8 + j];
        float s = sp[n];
        int q = 0;
        #pragma unroll
        for (int i = 0; i < 8; ++i) {
            Sxs[i] = fmaf(xr[i], s, Sxs[i]);
            #pragma unroll
            for (int j = i; j < 8; ++j) { Sxx[q] = fmaf(xr[i], xr[j], Sxx[q]); ++q; }
        }
        Sss = fmaf(s, s, Sss);
        #pragma unroll
        for (int m = 0; m < 6; ++m) {
            float cv = cp[m*NN + n];
            #pragma unroll
            for (int j = 0; j < 8; ++j) Praw[m*8+j] = fmaf(cv, xr[j], Praw[m*8+j]);
            Ps[m] = fmaf(cv, s, Ps[m]);
        }
    }
    #pragma unroll
    for (int q = 0; q < 36; ++q) part[q][lane] = Sxx[q];
    #pragma unroll
    for (int j = 0; j < 8; ++j) part[36+j][lane] = Sxs[j];
    part[44][lane] = Sss;
    #pragma unroll
    for (int q = 0; q < 48; ++q) part[45+q][lane] = Praw[q];
    #pragma unroll
    for (int m = 0; m < 6; ++m) part[93+m][lane] = Ps[m];
    __syncthreads();
    for (int q = lane; q < 99; q += 64) {
        float acc = 0.f;
        for (int l = 0; l < 64; ++l) acc += part[q][l];
        red[q] = acc;
    }
    __syncthreads();
    if (lane == 0) {
        int IDX[8][8];
        { int q = 0; for (int i = 0; i < 8; ++i) for (int j = i; j < 8; ++j) { IDX[i][j]=q; IDX[j][i]=q; ++q; } }
        float sumsq = 0.f;
        for (int i = 0; i < 8; ++i) sumsq += red[IDX[i][i]];
        double s = sqrt(128.0 / (double)sumsq);   // z = N*B*0.2^2
        double Sssd = (double)red[44];
        double G[9][9];
        for (int i = 0; i < 8; ++i)
            for (int j = 0; j < 8; ++j)
                G[i][j] = s*s*(double)red[IDX[i][j]] + s*((double)red[36+i] + (double)red[36+j]) + Sssd;
        for (int i = 0; i < 8; ++i) { G[i][8] = G[8][i] = s*(double)red[36+i] + Sssd; }
        G[8][8] = Sssd;
        double A[9][18];
        for (int i = 0; i < 9; ++i)
            for (int j = 0; j < 9; ++j) { A[i][j] = G[i][j]; A[i][9+j] = (i==j) ? 1.0 : 0.0; }
        for (int col = 0; col < 9; ++col) {
            int piv = col; double mx = fabs(A[col][col]);
            for (int r = col+1; r < 9; ++r) { double v = fabs(A[r][col]); if (v > mx) { mx = v; piv = r; } }
            if (piv != col) for (int j = 0; j < 18; ++j) { double tt = A[col][j]; A[col][j] = A[piv][j]; A[piv][j] = tt; }
            double pv = A[col][col];
            for (int j = 0; j < 18; ++j) A[col][j] /= pv;
            for (int r = 0; r < 9; ++r) if (r != col) {
                double f = A[r][col];
                for (int j = 0; j < 18; ++j) A[r][j] -= f*A[col][j];
            }
        }
        for (int m = 0; m < 6; ++m) {
            double P[9];
            for (int j = 0; j < 8; ++j) P[j] = s*(double)red[45 + m*8 + j] + (double)red[93+m];
            P[8] = (double)red[93+m];
            for (int j = 0; j < 9; ++j) {
                double qv = 0;
                for (int l = 0; l < 9; ++l) qv += P[l]*A[l][9+j];
                ws[2 + m*9 + j] = (float)qv;
            }
        }
        ws[1] = (float)s;
    }
    __syncthreads();
    // Cl[m][n] = cp[m][n] - s*(Q[m,:8].xraw[n,:]) - sp[n]*sum(Q[m,:])
    {
        float s = ws[1];
        for (int idx = lane; idx < 6*NN; idx += 64) {
            int m = idx / NN, n = idx - m*NN;
            float acc = 0.f, sq = 0.f;
            #pragma unroll
            for (int j = 0; j < 8; ++j) {
                float q = ws[2 + m*9 + j];
                acc = fmaf(q, ws[XRAW_OFF + n*8 + j], acc);
                sq += q;
            }
            sq += ws[2 + m*9 + 8];
            ws[CL_OFF + idx] = cp[idx] - s*acc - sp[n]*sq;
        }
    }
}

// A-fragment loader: W[m][k0..k0+7] fp32 -> fp16.
// Bias K-rows (paired with r rows written per step):
//   k=400: h_inp[m]  (r row 400 == 1)
//   k=401: ca_hi[m]  (r row 401 == et_hi)
//   k=402: ca_lo[m]  (r row 402 == et_hi)
//   k=403: ca_hi[m]  (r row 403 == et_lo)
// => MFMA accumulates ca*et to ~1e-6 (double-f16 product, fp32 accum).
// [validated round 9: absmax identical to the explicit-epilogue version]
__device__ __forceinline__ half8 load_wfrag(const float* __restrict__ Wg,
        const float* __restrict__ ws, const float* __restrict__ gg, int m, int k0)
{
    half8 a;
    if (k0 + 8 <= 400) {
        float4 x0 = *(const float4*)(Wg + m*400 + k0);
        float4 x1 = *(const float4*)(Wg + m*400 + k0 + 4);
        a[0]=(f16)x0.x; a[1]=(f16)x0.y; a[2]=(f16)x0.z; a[3]=(f16)x0.w;
        a[4]=(f16)x1.x; a[5]=(f16)x1.y; a[6]=(f16)x1.z; a[7]=(f16)x1.w;
    } else {
        float cav = (5.f + gg[m]) * (1.f/0.6968f);
        f16 chi = (f16)cav;
        float clo = cav - (float)chi;
        #pragma unroll
        for (int j = 0; j < 8; ++j) {
            int k = k0 + j;
            if (k < 400)       a[j] = (f16)Wg[m*400 + k];
            else if (k == 400) a[j] = (f16)ws[HINP_OFF + m];
            else if (k == 401) a[j] = chi;
            else if (k == 402) a[j] = (f16)clo;
            else if (k == 403) a[j] = chi;
            else               a[j] = (f16)0.f;
        }
    }
    return a;
}

__device__ __forceinline__ void store_r4(f16* dst, float r0, float r1, float r2, float r3) {
    union { f16 h[4]; ull u; } pk;
    pk.h[0] = (f16)r0; pk.h[1] = (f16)r1; pk.h[2] = (f16)r2; pk.h[3] = (f16)r3;
    *(ull*)dst = pk.u;
}

// one Euler step of the 2-link arm + kinematics; lanes 0..7 (one per batch)
__device__ __forceinline__ void arm_step_ode(const float* __restrict__ fr, int lane,
        float& t1, float& t2, float& d1, float& d2, float4& o4)
{
    const float MX[6] = {0.04f,-0.04f,0.f,0.f,0.028f,-0.035f};
    const float MY[6] = {0.f,0.f,0.025f,-0.025f,0.035f,-0.028f};
    float tq0 = 0.f, tq1 = 0.f;
    #pragma unroll
    for (int mm = 0; mm < 6; ++mm) {
        float f = fr[mm*8 + lane];
        tq0 = fmaf(f, MX[mm], tq0);
        tq1 = fmaf(f, MY[mm], tq1);
    }
    float cc2 = cosf(t2), ss2 = sinf(t2);
    float M11 = A1C + 2.f*A2C*cc2;
    float M12 = A3C + A2C*cc2;
    float h = A2C * ss2;
    float C1v = -h * d2 * (2.f*d1 + d2);
    float C2v = h * d1 * d1;
    float rr1 = tq0 - C1v - (0.05f*d1 + 0.025f*d2);
    float rr2 = tq1 - C2v - (0.025f*d1 + 0.05f*d2);
    float det = M11*A3C - M12*M12;
    float dd1 = (A3C*rr1 - M12*rr2) / det;
    float dd2 = (M11*rr2 - M12*rr1) / det;
    t1 += DHC * d1; t2 += DHC * d2;
    d1 += DHC * dd1; d2 += DHC * dd2;
    float t12 = t1 + t2, d12 = d1 + d2;
    float c1v = cosf(t1), s1v = sinf(t1);
    float c12 = cosf(t12), s12 = sinf(t12);
    o4.x = L1C*c1v + L2C*c12;
    o4.y = L1C*s1v + L2C*s12;
    o4.z = -L1C*s1v*d1 - L2C*s12*d12;
    o4.w = L1C*c1v*d1 + L2C*c12*d12;
}

// K3: whole recurrence on ONE CU via MFMA intrinsics; 8 waves (2 per SIMD).
// Round-10 structure + exec-masked B-reads: only lanes col<8 read the B
// fragment (the 64-lane read fetched duplicate bytes for col>=8 whose values
// only feed MFMA D-columns 8-15, which are never stored). bq stays 0 in
// col>=8 lanes -> those columns accumulate exactly 0. Halves B-read LDS
// traffic (104 reads/step: 1024B -> 512B each).
__global__ __launch_bounds__(TPB, 2) void k_run(const int* __restrict__ Tp,
        const float* __restrict__ Wg, const float* __restrict__ sp,
        const float* __restrict__ gg, float* __restrict__ ws,
        float* __restrict__ out)
{
    __shared__ __align__(16) f16 rpl[2][8][KP];       // r planes [batch(8)][neuron k(424)]
    __shared__ __align__(16) f16 at2[2][13][64][8];   // streamed tiles in fragment layout
    __shared__ float dbuf[10][48];                    // muscle delay ring (wave7)
    __shared__ float frc[2][48];                      // double-buffered: w7 writes, w2 reads
    __shared__ float4 obuf[32][8];                    // 32-step cart out-ring (wave2)

    const int tid = threadIdx.x;
    const int T = *Tp;
    const int wave = tid >> 6, lane = tid & 63;
    const int quad = lane >> 4, col = lane & 15;
    const int bcol = col & 7;
    const float s = ws[1];

    // ---- LDS init ----
    for (int idx = tid; idx < 2*8*KP; idx += TPB) ((f16*)rpl)[idx] = (f16)0.f;
    // streamed-tile staging: fragment layout [s][kt][lane][j]
    // s=0: W rows 384-399 incl. bias rows 400-403; s=1: muscle Cl (k>=400 -> 0)
    for (int idx = tid; idx < 2*13*512; idx += TPB) {
        int ss   = idx / (13*512);
        int rem  = idx - ss*(13*512);
        int kt   = rem >> 9;
        int rem2 = rem & 511;
        int ln   = rem2 >> 3, j = rem2 & 7;
        int c_   = ln & 15, q_ = ln >> 4;
        int k    = kt*32 + q_*8 + j;
        float v = 0.f;
        if (ss == 0) {
            if (k < 400) v = Wg[(384 + c_)*400 + k];
            else if (k == 400) v = ws[HINP_OFF + 384 + c_];
            else if (k <= 403) {
                float cav = (5.f + gg[384 + c_]) * (1.f/0.6968f);
                f16 chi = (f16)cav;
                v = (k == 402) ? (cav - (float)chi) : (float)chi;
            }
        } else {
            if (c_ < 6 && k < 400) v = ws[CL_OFF + c_*400 + k];
        }
        ((f16*)at2)[idx] = (f16)v;
    }
    for (int idx = tid; idx < 480; idx += TPB) ((float*)dbuf)[idx] = 0.f;
    for (int idx = tid; idx < 96; idx += TPB) ((float*)frc)[idx] = 0.f;
    __syncthreads();
    if (tid < 8) {
        // plane0 rows 400-403: {1, et(step0)_hi, et(step0)_hi, et(step0)_lo}
        float et1 = __expf(-1.f/60.f) - __expf(-1.f/6.f);
        f16 eh = (f16)et1;
        f16 el = (f16)(et1 - (float)eh);
        rpl[0][tid][400] = (f16)1.f; rpl[0][tid][401] = eh;
        rpl[0][tid][402] = eh;       rpl[0][tid][403] = el;
        rpl[1][tid][400] = (f16)1.f;   // plane1 rows 401-403 written during step 0
    }

    // ---- register A-tiles: af[t][kt], tiles 3w..3w+2 (incl. bias rows via load_wfrag) ----
    half8 af[3][13];
    #pragma unroll
    for (int t = 0; t < 3; ++t) {
        #pragma unroll
        for (int kt = 0; kt < 13; ++kt)
            af[t][kt] = load_wfrag(Wg, ws, gg, (3*wave + t)*16 + col, kt*32 + quad*8);
    }

    // ---- state init: acc = 19*x0 (x lives in accumulator scaled by (1-tau)/tau) ----
    const int nT = (wave == 0) ? 4 : 3;    // epilogue tiles (wave0's t=3 = rows 384-399)
    f32x4 acc[4];
    float msc[4] = {0.f, 0.f, 0.f, 0.f};
    float t1 = 1.f, t2 = 1.f, d1 = 0.f, d2 = 0.f;   // wave2 lanes 0..7
    #pragma unroll
    for (int t = 0; t < 4; ++t)
        #pragma unroll
        for (int r = 0; r < 4; ++r) acc[t][r] = 0.f;
    #pragma unroll
    for (int t = 0; t < 4; ++t) {
        if (t < nT) {
            int n0 = (t < 3) ? (3*wave + t)*16 + quad*4 : 384 + quad*4;
            float rr[4];
            #pragma unroll
            for (int r = 0; r < 4; ++r) {
                float xa = sp[n0+r] + s*ws[XRAW_OFF + (n0+r)*8 + bcol];
                acc[t][r] = 19.f*xa;
                rr[r] = fmaxf(xa, 0.f);
            }
            if (col < 8)
                store_r4(&rpl[0][col][n0], rr[0], rr[1], rr[2], rr[3]);
        }
    }
    __syncthreads();

    // persistent B fragment; col>=8 lanes keep 0 forever (their D-columns are unused)
    half8 bq;
    #pragma unroll
    for (int j = 0; j < 8; ++j) bq[j] = (f16)0.f;
    const bool bact = (col < 8);

    // ---- step loop ----
    for (int i = 0; i < T; ++i) {
        const int p = i & 1;
        // wave2: deferred arm ODE for step i-1 (frc[(i-1)&1] written by wave7 last step)
        if (wave == 2 && i > 0) {
            if (lane < 8) {
                float4 o4;
                arm_step_ode(frc[(i-1) & 1], lane, t1, t2, d1, d2, o4);
                obuf[(i-1) & 31][lane] = o4;
            }
            if ((i & 31) == 0) {   // flush steps i-32 .. i-1
                asm volatile("s_waitcnt lgkmcnt(0)" ::: "memory");
                #pragma unroll
                for (int k2 = 0; k2 < 4; ++k2) {
                    int idx = lane + (k2 << 6);
                    int so = idx >> 3, b = idx & 7;
                    *(float4*)(out + ((size_t)(i - 32 + so)*8 + b)*4) = obuf[so][b];
                }
            }
        }
        if (wave == 7) { acc[3][0]=0.f; acc[3][1]=0.f; acc[3][2]=0.f; acc[3][3]=0.f; }

        if (wave == 0 || wave == 7) {
            const int sidx = (wave == 7) ? 1 : 0;
            #pragma unroll
            for (int kt = 0; kt < 13; ++kt) {
                if (bact) bq = *(const half8*)&rpl[p][bcol][kt*32 + quad*8];
                half8 a3 = *(const half8*)&at2[sidx][kt][lane][0];
                acc[0] = __builtin_amdgcn_mfma_f32_16x16x32_f16(af[0][kt], bq, acc[0], 0, 0, 0);
                acc[1] = __builtin_amdgcn_mfma_f32_16x16x32_f16(af[1][kt], bq, acc[1], 0, 0, 0);
                acc[2] = __builtin_amdgcn_mfma_f32_16x16x32_f16(af[2][kt], bq, acc[2], 0, 0, 0);
                acc[3] = __builtin_amdgcn_mfma_f32_16x16x32_f16(a3,       bq, acc[3], 0, 0, 0);
            }
        } else {
            #pragma unroll
            for (int kt = 0; kt < 13; ++kt) {
                if (bact) bq = *(const half8*)&rpl[p][bcol][kt*32 + quad*8];
                acc[0] = __builtin_amdgcn_mfma_f32_16x16x32_f16(af[0][kt], bq, acc[0], 0, 0, 0);
                acc[1] = __builtin_amdgcn_mfma_f32_16x16x32_f16(af[1][kt], bq, acc[1], 0, 0, 0);
                acc[2] = __builtin_amdgcn_mfma_f32_16x16x32_f16(af[2][kt], bq, acc[2], 0, 0, 0);
            }
        }

        // epilogue: acc already holds y = W.r + hinp + ca*et + 19*x_prev
        #pragma unroll
        for (int t = 0; t < 4; ++t) {
            if (t < nT) {
                int n0 = (t < 3) ? (3*wave + t)*16 + quad*4 : 384 + quad*4;
                float rr[4];
                #pragma unroll
                for (int r = 0; r < 4; ++r) {
                    float ya = acc[t][r];
                    rr[r] = fmaxf(TAU_X*ya, 0.f);
                    acc[t][r] = 0.95f*ya;
                }
                if (col < 8)
                    store_r4(&rpl[p^1][col][n0], rr[0], rr[1], rr[2], rr[3]);
            }
        }
        // wave7: muscle update from streamed Cl accumulator (slot 3)
        if (wave == 7 && col < 8) {
            int sl = i - (i/10)*10;
            #pragma unroll
            for (int r = 0; r < 4; ++r) {
                int m = quad*4 + r;
                if (m < 6) {
                    float mi = acc[3][r] * TAU_M;
                    float mnew = (mi > 0.f ? mi : 0.4f*mi) + 0.8f*msc[r];
                    msc[r] = mnew;
                    float delayed = dbuf[sl][m*8 + col];
                    dbuf[sl][m*8 + col] = mnew;
                    frc[i & 1][m*8 + col] = 40.f * fmaxf(delayed, 0.f);
                }
            }
        }
        // wave1: write next plane's bias rows {1, et(i+1)_hi, et(i+1)_hi, et(i+1)_lo}
        if (wave == 1 && col < 8) {
            float tf = (float)(i + 2);
            float etn = __expf(tf * (-1.f/60.f)) - __expf(tf * (-1.f/6.f));
            f16 eh = (f16)etn;
            f16 el = (f16)(etn - (float)eh);
            union { f16 h[4]; ull u; } pk;
            pk.h[0] = (f16)1.f; pk.h[1] = eh; pk.h[2] = eh; pk.h[3] = el;
            *(ull*)&rpl[p^1][col][400] = pk.u;
        }
        __syncthreads();
    }

    // wave2: final deferred ODE for step T-1 + residual flush
    if (wave == 2) {
        if (lane < 8) {
            float4 o4;
            arm_step_ode(frc[(T-1) & 1], lane, t1, t2, d1, d2, o4);
            obuf[(T-1) & 31][lane] = o4;
        }
        asm volatile("s_waitcnt lgkmcnt(0)" ::: "memory");
        const int i0 = (T-1) & ~31;
        const int cnt = T - i0;           // 1..32 steps remaining
        for (int idx = lane; idx < cnt*8; idx += 64) {
            int so = idx >> 3, b = idx & 7;
            *(float4*)(out + ((size_t)(i0 + so)*8 + b)*4) = obuf[so][b];
        }
    }
}

extern "C" void kernel_launch(void* const* d_in, const int* in_sizes, int n_in,
                              void* d_out, int out_size, void* d_ws, size_t ws_size,
                              hipStream_t stream) {
    (void)in_sizes; (void)n_in; (void)out_size; (void)ws_size;
    const int*   Tp   = (const int*)d_in[0];
    const float* des  = (const float*)d_in[1];
    const float* W    = (const float*)d_in[3];
    const float* iw   = (const float*)d_in[4];
    const float* xp   = (const float*)d_in[5];
    const float* cp   = (const float*)d_in[6];
    const float* sp   = (const float*)d_in[7];
    const float* gg   = (const float*)d_in[8];
    const float* topo = (const float*)d_in[9];
    float* ws  = (float*)d_ws;
    float* out = (float*)d_out;

    k_pre1<<<NN, 64, 0, stream>>>(topo, xp, W, sp, iw, des, ws);
    k_pre2<<<1, 64, 0, stream>>>(cp, sp, ws);
    k_run<<<1, TPB, 0, stream>>>(Tp, W, sp, gg, ws, out);
}

// Round 12
// 1660.632 us; speedup vs baseline: 1.1165x; 1.1165x over previous
//
#include <hip/hip_runtime.h>
#include <math.h>

// Problem constants
#define NN 400
#define TPB 512          // 8 waves, 2 waves/SIMD; 3 register A-tiles/wave (156 regs, fits),
                         // 2 static tiles streamed from LDS; ca*et bias fused into K-rows 401-403
#define KP 424           // padded K stride in fp16 elems

// workspace layout (32-bit indices)
#define XRAW_OFF 1024    // 3200 floats
#define HINP_OFF 4224    // 400 floats
#define CL_OFF   4624    // 2400 floats (projected readout c from k_pre2)

#define TAU_X 0.05f
#define TAU_M 0.2f
#define A1C 0.16f
#define A2C 0.048f
#define A3C 0.045f
#define DHC 0.001f
#define L1C 0.3f
#define L2C 0.33f

typedef unsigned long long ull;
typedef _Float16 f16;
typedef _Float16 __attribute__((ext_vector_type(8))) half8;
typedef float __attribute__((ext_vector_type(4))) f32x4;

// K1: xraw[n][b] = (top_obs @ xstars_prms)[n,b] + xstars_tar[b][n]; hinp[n] = spont[n]-(W@spont)[n]
__global__ __launch_bounds__(64) void k_pre1(const float* __restrict__ topo,
        const float* __restrict__ xp, const float* __restrict__ W,
        const float* __restrict__ sp, const float* __restrict__ iw,
        const float* __restrict__ des, float* __restrict__ ws)
{
    const int n = blockIdx.x, lane = threadIdx.x;
    float a0=0,a1=0,a2=0,a3=0,a4=0,a5=0,a6=0,a7=0, ah=0;
    for (int k = lane; k < NN; k += 64) {
        float to = topo[n*NN + k];
        float wv = W[n*NN + k];
        float s  = sp[k];
        const float* xr = xp + k*8;
        a0 = fmaf(to, xr[0], a0); a1 = fmaf(to, xr[1], a1);
        a2 = fmaf(to, xr[2], a2); a3 = fmaf(to, xr[3], a3);
        a4 = fmaf(to, xr[4], a4); a5 = fmaf(to, xr[5], a5);
        a6 = fmaf(to, xr[6], a6); a7 = fmaf(to, xr[7], a7);
        ah = fmaf(wv, s, ah);
    }
    #pragma unroll
    for (int m = 1; m < 64; m <<= 1) {
        a0 += __shfl_xor(a0, m, 64); a1 += __shfl_xor(a1, m, 64);
        a2 += __shfl_xor(a2, m, 64); a3 += __shfl_xor(a3, m, 64);
        a4 += __shfl_xor(a4, m, 64); a5 += __shfl_xor(a5, m, 64);
        a6 += __shfl_xor(a6, m, 64); a7 += __shfl_xor(a7, m, 64);
        ah += __shfl_xor(ah, m, 64);
    }
    if (lane == 0) {
        float av[8] = {a0,a1,a2,a3,a4,a5,a6,a7};
        float w0 = iw[n*10 + 0], w1 = iw[n*10 + 1];
        #pragma unroll
        for (int b = 0; b < 8; ++b) {
            float j0 = des[2*b]   - 0.25f;
            float j1 = des[2*b+1] - 0.25f;
            ws[XRAW_OFF + n*8 + b] = av[b] + j0*w0 + j1*w1;
        }
        ws[HINP_OFF + n] = sp[n] - ah;
    }
}

// K2: scale s, Gram solve (fp64), Q, Cl precompute
__global__ __launch_bounds__(64) void k_pre2(const float* __restrict__ cp,
        const float* __restrict__ sp, float* __restrict__ ws)
{
    __shared__ float part[99][65];
    __shared__ float red[99];
    const int lane = threadIdx.x;
    float Sxx[36], Sxs[8], Praw[48], Ps[6];
    float Sss = 0.f;
    #pragma unroll
    for (int q = 0; q < 36; ++q) Sxx[q] = 0.f;
    #pragma unroll
    for (int q = 0; q < 8; ++q) Sxs[q] = 0.f;
    #pragma unroll
    for (int q = 0; q < 48; ++q) Praw[q] = 0.f;
    #pragma unroll
    for (int q = 0; q < 6; ++q) Ps[q] = 0.f;

    for (int n = lane; n < NN; n += 64) {
        float xr[8];
        #pragma unroll
        for (int j = 0; j < 8; ++j) xr[j] = ws[XRAW_OFF + n*8 + j];
        float s = sp[n];
        int q = 0;
        #pragma unroll
        for (int i = 0; i < 8; ++i) {
            Sxs[i] = fmaf(xr[i], s, Sxs[i]);
            #pragma unroll
            for (int j = i; j < 8; ++j) { Sxx[q] = fmaf(xr[i], xr[j], Sxx[q]); ++q; }
        }
        Sss = fmaf(s, s, Sss);
        #pragma unroll
        for (int m = 0; m < 6; ++m) {
            float cv = cp[m*NN + n];
            #pragma unroll
            for (int j = 0; j < 8; ++j) Praw[m*8+j] = fmaf(cv, xr[j], Praw[m*8+j]);
            Ps[m] = fmaf(cv, s, Ps[m]);
        }
    }
    #pragma unroll
    for (int q = 0; q < 36; ++q) part[q][lane] = Sxx[q];
    #pragma unroll
    for (int j = 0; j < 8; ++j) part[36+j][lane] = Sxs[j];
    part[44][lane] = Sss;
    #pragma unroll
    for (int q = 0; q < 48; ++q) part[45+q][lane] = Praw[q];
    #pragma unroll
    for (int m = 0; m < 6; ++m) part[93+m][lane] = Ps[m];
    __syncthreads();
    for (int q = lane; q < 99; q += 64) {
        float acc = 0.f;
        for (int l = 0; l < 64; ++l) acc += part[q][l];
        red[q] = acc;
    }
    __syncthreads();
    if (lane == 0) {
        int IDX[8][8];
        { int q = 0; for (int i = 0; i < 8; ++i) for (int j = i; j < 8; ++j) { IDX[i][j]=q; IDX[j][i]=q; ++q; } }
        float sumsq = 0.f;
        for (int i = 0; i < 8; ++i) sumsq += red[IDX[i][i]];
        double s = sqrt(128.0 / (double)sumsq);   // z = N*B*0.2^2
        double Sssd = (double)red[44];
        double G[9][9];
        for (int i = 0; i < 8; ++i)
            for (int j = 0; j < 8; ++j)
                G[i][j] = s*s*(double)red[IDX[i][j]] + s*((double)red[36+i] + (double)red[36+j]) + Sssd;
        for (int i = 0; i < 8; ++i) { G[i][8] = G[8][i] = s*(double)red[36+i] + Sssd; }
        G[8][8] = Sssd;
        double A[9][18];
        for (int i = 0; i < 9; ++i)
            for (int j = 0; j < 9; ++j) { A[i][j] = G[i][j]; A[i][9+j] = (i==j) ? 1.0 : 0.0; }
        for (int col = 0; col < 9; ++col) {
            int piv = col; double mx = fabs(A[col][col]);
            for (int r = col+1; r < 9; ++r) { double v = fabs(A[r][col]); if (v > mx) { mx = v; piv = r; } }
            if (piv != col) for (int j = 0; j < 18; ++j) { double tt = A[col][j]; A[col][j] = A[piv][j]; A[piv][j] = tt; }
            double pv = A[col][col];
            for (int j = 0; j < 18; ++j) A[col][j] /= pv;
            for (int r = 0; r < 9; ++r) if (r != col) {
                double f = A[r][col];
                for (int j = 0; j < 18; ++j) A[r][j] -= f*A[col][j];
            }
        }
        for (int m = 0; m < 6; ++m) {
            double P[9];
            for (int j = 0; j < 8; ++j) P[j] = s*(double)red[45 + m*8 + j] + (double)red[93+m];
            P[8] = (double)red[93+m];
            for (int j = 0; j < 9; ++j) {
                double qv = 0;
                for (int l = 0; l < 9; ++l) qv += P[l]*A[l][9+j];
                ws[2 + m*9 + j] = (float)qv;
            }
        }
        ws[1] = (float)s;
    }
    __syncthreads();
    // Cl[m][n] = cp[m][n] - s*(Q[m,:8].xraw[n,:]) - sp[n]*sum(Q[m,:])
    {
        float s = ws[1];
        for (int idx = lane; idx < 6*NN; idx += 64) {
            int m = idx / NN, n = idx - m*NN;
            float acc = 0.f, sq = 0.f;
            #pragma unroll
            for (int j = 0; j < 8; ++j) {
                float q = ws[2 + m*9 + j];
                acc = fmaf(q, ws[XRAW_OFF + n*8 + j], acc);
                sq += q;
            }
            sq += ws[2 + m*9 + 8];
            ws[CL_OFF + idx] = cp[idx] - s*acc - sp[n]*sq;
        }
    }
}

// A-fragment loader: W[m][k0..k0+7] fp32 -> fp16.
// Bias K-rows (paired with r rows written per step):
//   k=400: h_inp[m]  (r row 400 == 1)
//   k=401: ca_hi[m]  (r row 401 == et_hi)
//   k=402: ca_lo[m]  (r row 402 == et_hi)
//   k=403: ca_hi[m]  (r row 403 == et_lo)
// => MFMA accumulates ca*et to ~1e-6 (double-f16 product, fp32 accum).
// [validated round 9: absmax identical to the explicit-epilogue version]
__device__ __forceinline__ half8 load_wfrag(const float* __restrict__ Wg,
        const float* __restrict__ ws, const float* __restrict__ gg, int m, int k0)
{
    half8 a;
    if (k0 + 8 <= 400) {
        float4 x0 = *(const float4*)(Wg + m*400 + k0);
        float4 x1 = *(const float4*)(Wg + m*400 + k0 + 4);
        a[0]=(f16)x0.x; a[1]=(f16)x0.y; a[2]=(f16)x0.z; a[3]=(f16)x0.w;
        a[4]=(f16)x1.x; a[5]=(f16)x1.y; a[6]=(f16)x1.z; a[7]=(f16)x1.w;
    } else {
        float cav = (5.f + gg[m]) * (1.f/0.6968f);
        f16 chi = (f16)cav;
        float clo = cav - (float)chi;
        #pragma unroll
        for (int j = 0; j < 8; ++j) {
            int k = k0 + j;
            if (k < 400)       a[j] = (f16)Wg[m*400 + k];
            else if (k == 400) a[j] = (f16)ws[HINP_OFF + m];
            else if (k == 401) a[j] = chi;
            else if (k == 402) a[j] = (f16)clo;
            else if (k == 403) a[j] = chi;
            else               a[j] = (f16)0.f;
        }
    }
    return a;
}

__device__ __forceinline__ void store_r4(f16* dst, float r0, float r1, float r2, float r3) {
    union { f16 h[4]; ull u; } pk;
    pk.h[0] = (f16)r0; pk.h[1] = (f16)r1; pk.h[2] = (f16)r2; pk.h[3] = (f16)r3;
    *(ull*)dst = pk.u;
}

// one Euler step of the 2-link arm + kinematics; lanes 0..7 (one per batch)
__device__ __forceinline__ void arm_step_ode(const float* __restrict__ fr, int lane,
        float& t1, float& t2, float& d1, float& d2, float4& o4)
{
    const float MX[6] = {0.04f,-0.04f,0.f,0.f,0.028f,-0.035f};
    const float MY[6] = {0.f,0.f,0.025f,-0.025f,0.035f,-0.028f};
    float tq0 = 0.f, tq1 = 0.f;
    #pragma unroll
    for (int mm = 0; mm < 6; ++mm) {
        float f = fr[mm*8 + lane];
        tq0 = fmaf(f, MX[mm], tq0);
        tq1 = fmaf(f, MY[mm], tq1);
    }
    float cc2 = cosf(t2), ss2 = sinf(t2);
    float M11 = A1C + 2.f*A2C*cc2;
    float M12 = A3C + A2C*cc2;
    float h = A2C * ss2;
    float C1v = -h * d2 * (2.f*d1 + d2);
    float C2v = h * d1 * d1;
    float rr1 = tq0 - C1v - (0.05f*d1 + 0.025f*d2);
    float rr2 = tq1 - C2v - (0.025f*d1 + 0.05f*d2);
    float det = M11*A3C - M12*M12;
    float dd1 = (A3C*rr1 - M12*rr2) / det;
    float dd2 = (M11*rr2 - M12*rr1) / det;
    t1 += DHC * d1; t2 += DHC * d2;
    d1 += DHC * dd1; d2 += DHC * dd2;
    float t12 = t1 + t2, d12 = d1 + d2;
    float c1v = cosf(t1), s1v = sinf(t1);
    float c12 = cosf(t12), s12 = sinf(t12);
    o4.x = L1C*c1v + L2C*c12;
    o4.y = L1C*s1v + L2C*s12;
    o4.z = -L1C*s1v*d1 - L2C*s12*d12;
    o4.w = L1C*c1v*d1 + L2C*c12*d12;
}

// K3: whole recurrence on ONE CU via MFMA intrinsics; 8 waves (2 per SIMD).
// Best-verified structure (round 10, k_run 1410 us):
//  - 3 register A-tiles/wave (af[3][13] = 156 regs; fits the 256-reg budget
//    at 2 waves/EU with NO spill - FETCH_SIZE clean at ~431 KB)
//  - waves 0/7 stream their 4th operand per kt from at2 (fragment layout,
//    conflict-free b128)
//  - ca*et bias rides MFMA K-rows 401-403 (double-f16, validated bit-exact);
//    epilogue is r=relu(0.05*acc); acc*=0.95 with no expf in the hot waves;
//    wave1 writes the 4 bias f16s {1, eh, eh, el} for step i+1 each step
//  - wave2: one-step-deferred arm ODE + 32-step out-ring flush
//  - wave7: muscle state (leaky+decay, 10-step delay ring, frc double-buffer)
// NOTE (r11): exec-masking the B-reads to col<8 halves SQ_LDS_BANK_CONFLICT
// but REGRESSES time 14% - LDS bank cycles are not on the critical path;
// full-width 64-lane b128 reads are the faster form. Do not re-mask.
__global__ __launch_bounds__(TPB, 2) void k_run(const int* __restrict__ Tp,
        const float* __restrict__ Wg, const float* __restrict__ sp,
        const float* __restrict__ gg, float* __restrict__ ws,
        float* __restrict__ out)
{
    __shared__ __align__(16) f16 rpl[2][8][KP];       // r planes [batch(8)][neuron k(424)]
    __shared__ __align__(16) f16 at2[2][13][64][8];   // streamed tiles in fragment layout
    __shared__ float dbuf[10][48];                    // muscle delay ring (wave7)
    __shared__ float frc[2][48];                      // double-buffered: w7 writes, w2 reads
    __shared__ float4 obuf[32][8];                    // 32-step cart out-ring (wave2)

    const int tid = threadIdx.x;
    const int T = *Tp;
    const int wave = tid >> 6, lane = tid & 63;
    const int quad = lane >> 4, col = lane & 15;
    const int bcol = col & 7;
    const float s = ws[1];

    // ---- LDS init ----
    for (int idx = tid; idx < 2*8*KP; idx += TPB) ((f16*)rpl)[idx] = (f16)0.f;
    // streamed-tile staging: fragment layout [s][kt][lane][j]
    // s=0: W rows 384-399 incl. bias rows 400-403; s=1: muscle Cl (k>=400 -> 0)
    for (int idx = tid; idx < 2*13*512; idx += TPB) {
        int ss   = idx / (13*512);
        int rem  = idx - ss*(13*512);
        int kt   = rem >> 9;
        int rem2 = rem & 511;
        int ln   = rem2 >> 3, j = rem2 & 7;
        int c_   = ln & 15, q_ = ln >> 4;
        int k    = kt*32 + q_*8 + j;
        float v = 0.f;
        if (ss == 0) {
            if (k < 400) v = Wg[(384 + c_)*400 + k];
            else if (k == 400) v = ws[HINP_OFF + 384 + c_];
            else if (k <= 403) {
                float cav = (5.f + gg[384 + c_]) * (1.f/0.6968f);
                f16 chi = (f16)cav;
                v = (k == 402) ? (cav - (float)chi) : (float)chi;
            }
        } else {
            if (c_ < 6 && k < 400) v = ws[CL_OFF + c_*400 + k];
        }
        ((f16*)at2)[idx] = (f16)v;
    }
    for (int idx = tid; idx < 480; idx += TPB) ((float*)dbuf)[idx] = 0.f;
    for (int idx = tid; idx < 96; idx += TPB) ((float*)frc)[idx] = 0.f;
    __syncthreads();
    if (tid < 8) {
        // plane0 rows 400-403: {1, et(step0)_hi, et(step0)_hi, et(step0)_lo}
        float et1 = __expf(-1.f/60.f) - __expf(-1.f/6.f);
        f16 eh = (f16)et1;
        f16 el = (f16)(et1 - (float)eh);
        rpl[0][tid][400] = (f16)1.f; rpl[0][tid][401] = eh;
        rpl[0][tid][402] = eh;       rpl[0][tid][403] = el;
        rpl[1][tid][400] = (f16)1.f;   // plane1 rows 401-403 written during step 0
    }

    // ---- register A-tiles: af[t][kt], tiles 3w..3w+2 (incl. bias rows via load_wfrag) ----
    half8 af[3][13];
    #pragma unroll
    for (int t = 0; t < 3; ++t) {
        #pragma unroll
        for (int kt = 0; kt < 13; ++kt)
            af[t][kt] = load_wfrag(Wg, ws, gg, (3*wave + t)*16 + col, kt*32 + quad*8);
    }

    // ---- state init: acc = 19*x0 (x lives in accumulator scaled by (1-tau)/tau) ----
    const int nT = (wave == 0) ? 4 : 3;    // epilogue tiles (wave0's t=3 = rows 384-399)
    f32x4 acc[4];
    float msc[4] = {0.f, 0.f, 0.f, 0.f};
    float t1 = 1.f, t2 = 1.f, d1 = 0.f, d2 = 0.f;   // wave2 lanes 0..7
    #pragma unroll
    for (int t = 0; t < 4; ++t)
        #pragma unroll
        for (int r = 0; r < 4; ++r) acc[t][r] = 0.f;
    #pragma unroll
    for (int t = 0; t < 4; ++t) {
        if (t < nT) {
            int n0 = (t < 3) ? (3*wave + t)*16 + quad*4 : 384 + quad*4;
            float rr[4];
            #pragma unroll
            for (int r = 0; r < 4; ++r) {
                float xa = sp[n0+r] + s*ws[XRAW_OFF + (n0+r)*8 + bcol];
                acc[t][r] = 19.f*xa;
                rr[r] = fmaxf(xa, 0.f);
            }
            if (col < 8)
                store_r4(&rpl[0][col][n0], rr[0], rr[1], rr[2], rr[3]);
        }
    }
    __syncthreads();

    // ---- step loop ----
    for (int i = 0; i < T; ++i) {
        const int p = i & 1;
        // wave2: deferred arm ODE for step i-1 (frc[(i-1)&1] written by wave7 last step)
        if (wave == 2 && i > 0) {
            if (lane < 8) {
                float4 o4;
                arm_step_ode(frc[(i-1) & 1], lane, t1, t2, d1, d2, o4);
                obuf[(i-1) & 31][lane] = o4;
            }
            if ((i & 31) == 0) {   // flush steps i-32 .. i-1
                asm volatile("s_waitcnt lgkmcnt(0)" ::: "memory");
                #pragma unroll
                for (int k2 = 0; k2 < 4; ++k2) {
                    int idx = lane + (k2 << 6);
                    int so = idx >> 3, b = idx & 7;
                    *(float4*)(out + ((size_t)(i - 32 + so)*8 + b)*4) = obuf[so][b];
                }
            }
        }
        if (wave == 7) { acc[3][0]=0.f; acc[3][1]=0.f; acc[3][2]=0.f; acc[3][3]=0.f; }

        if (wave == 0 || wave == 7) {
            const int sidx = (wave == 7) ? 1 : 0;
            #pragma unroll
            for (int kt = 0; kt < 13; ++kt) {
                half8 b  = *(const half8*)&rpl[p][bcol][kt*32 + quad*8];
                half8 a3 = *(const half8*)&at2[sidx][kt][lane][0];
                acc[0] = __builtin_amdgcn_mfma_f32_16x16x32_f16(af[0][kt], b, acc[0], 0, 0, 0);
                acc[1] = __builtin_amdgcn_mfma_f32_16x16x32_f16(af[1][kt], b, acc[1], 0, 0, 0);
                acc[2] = __builtin_amdgcn_mfma_f32_16x16x32_f16(af[2][kt], b, acc[2], 0, 0, 0);
                acc[3] = __builtin_amdgcn_mfma_f32_16x16x32_f16(a3,       b, acc[3], 0, 0, 0);
            }
        } else {
            #pragma unroll
            for (int kt = 0; kt < 13; ++kt) {
                half8 b = *(const half8*)&rpl[p][bcol][kt*32 + quad*8];
                acc[0] = __builtin_amdgcn_mfma_f32_16x16x32_f16(af[0][kt], b, acc[0], 0, 0, 0);
                acc[1] = __builtin_amdgcn_mfma_f32_16x16x32_f16(af[1][kt], b, acc[1], 0, 0, 0);
                acc[2] = __builtin_amdgcn_mfma_f32_16x16x32_f16(af[2][kt], b, acc[2], 0, 0, 0);
            }
        }

        // epilogue: acc already holds y = W.r + hinp + ca*et + 19*x_prev
        #pragma unroll
        for (int t = 0; t < 4; ++t) {
            if (t < nT) {
                int n0 = (t < 3) ? (3*wave + t)*16 + quad*4 : 384 + quad*4;
                float rr[4];
                #pragma unroll
                for (int r = 0; r < 4; ++r) {
                    float ya = acc[t][r];
                    rr[r] = fmaxf(TAU_X*ya, 0.f);
                    acc[t][r] = 0.95f*ya;
                }
                if (col < 8)
                    store_r4(&rpl[p^1][col][n0], rr[0], rr[1], rr[2], rr[3]);
            }
        }
        // wave7: muscle update from streamed Cl accumulator (slot 3)
        if (wave == 7 && col < 8) {
            int sl = i - (i/10)*10;
            #pragma unroll
            for (int r = 0; r < 4; ++r) {
                int m = quad*4 + r;
                if (m < 6) {
                    float mi = acc[3][r] * TAU_M;
                    float mnew = (mi > 0.f ? mi : 0.4f*mi) + 0.8f*msc[r];
                    msc[r] = mnew;
                    float delayed = dbuf[sl][m*8 + col];
                    dbuf[sl][m*8 + col] = mnew;
                    frc[i & 1][m*8 + col] = 40.f * fmaxf(delayed, 0.f);
                }
            }
        }
        // wave1: write next plane's bias rows {1, et(i+1)_hi, et(i+1)_hi, et(i+1)_lo}
        if (wave == 1 && col < 8) {
            float tf = (float)(i + 2);
            float etn = __expf(tf * (-1.f/60.f)) - __expf(tf * (-1.f/6.f));
            f16 eh = (f16)etn;
            f16 el = (f16)(etn - (float)eh);
            union { f16 h[4]; ull u; } pk;
            pk.h[0] = (f16)1.f; pk.h[1] = eh; pk.h[2] = eh; pk.h[3] = el;
            *(ull*)&rpl[p^1][col][400] = pk.u;
        }
        __syncthreads();
    }

    // wave2: final deferred ODE for step T-1 + residual flush
    if (wave == 2) {
        if (lane < 8) {
            float4 o4;
            arm_step_ode(frc[(T-1) & 1], lane, t1, t2, d1, d2, o4);
            obuf[(T-1) & 31][lane] = o4;
        }
        asm volatile("s_waitcnt lgkmcnt(0)" ::: "memory");
        const int i0 = (T-1) & ~31;
        const int cnt = T - i0;           // 1..32 steps remaining
        for (int idx = lane; idx < cnt*8; idx += 64) {
            int so = idx >> 3, b = idx & 7;
            *(float4*)(out + ((size_t)(i0 + so)*8 + b)*4) = obuf[so][b];
        }
    }
}

extern "C" void kernel_launch(void* const* d_in, const int* in_sizes, int n_in,
                              void* d_out, int out_size, void* d_ws, size_t ws_size,
                              hipStream_t stream) {
    (void)in_sizes; (void)n_in; (void)out_size; (void)ws_size;
    const int*   Tp   = (const int*)d_in[0];
    const float* des  = (const float*)d_in[1];
    const float* W    = (const float*)d_in[3];
    const float* iw   = (const float*)d_in[4];
    const float* xp   = (const float*)d_in[5];
    const float* cp   = (const float*)d_in[6];
    const float* sp   = (const float*)d_in[7];
    const float* gg   = (const float*)d_in[8];
    const float* topo = (const float*)d_in[9];
    float* ws  = (float*)d_ws;
    float* out = (float*)d_out;

    k_pre1<<<NN, 64, 0, stream>>>(topo, xp, W, sp, iw, des, ws);
    k_pre2<<<1, 64, 0, stream>>>(cp, sp, ws);
    k_run<<<1, TPB, 0, stream>>>(Tp, W, sp, gg, ws, out);
}